// Round 7
// baseline (241.747 us; speedup 1.0000x reference)
//
#include <hip/hip_runtime.h>

#define DEVINL __device__ __forceinline__

DEVINL float gelu_exact(float x){ return 0.5f * x * (1.0f + erff(x * 0.70710678118654752f)); }
DEVINL float lrelu02(float x){ return x >= 0.0f ? x : 0.2f * x; }

// B=4 S=16 N=400 -> 64 graph batches, 25600 node-rows, 1600 sequences
#define NN    400
#define NROWS 25600
#define NSEQ  1600

// ws byte offsets (non-overlapping)
#define OFF_MASK 0u
#define OFF_HP1  160000u
#define OFF_ES1  1798400u
#define OFF_ED1  2208000u
#define OFF_X1   2617600u
#define OFF_HP2  4256000u
#define OFF_ES2  7532800u
#define OFF_ED2  7942400u
#define OFF_H2   8352000u

// K1: mask[i][j] = cos(emb_i, emb_j) > 0.5 ; block per i, thread per j
__global__ __launch_bounds__(512) void k_mask2(const float* __restrict__ emb,
                                               unsigned char* __restrict__ mask){
  int i = blockIdx.x, j = threadIdx.x;
  if (j >= NN) return;
  double si = 0.0, sj = 0.0, dp = 0.0;
  for (int k = 0; k < 16; k++){
    double a = (double)emb[i * 16 + k];
    double b = (double)emb[j * 16 + k];
    si += a * a; sj += b * b; dp += a * b;
  }
  double c = dp / (sqrt(fmax(si, 1e-12)) * sqrt(fmax(sj, 1e-12)));
  mask[i * NN + j] = (c > 0.5) ? (unsigned char)1 : (unsigned char)0;
}

// K2: hp1[row,c] = proj(x[row]) dot g1_w[:,c]; one THREAD per output element
__global__ __launch_bounds__(256) void k_pre1a(const float* __restrict__ x,
    const float* __restrict__ pw, const float* __restrict__ pb,
    const float* __restrict__ g1w, float* __restrict__ hp1){
  int idx = blockIdx.x * 256 + threadIdx.x;           // 409600
  if (idx >= NROWS * 16) return;
  int row = idx >> 4, c = idx & 15;
  float x0 = x[row*3+0], x1 = x[row*3+1], x2 = x[row*3+2];
  float a = 0.f;
  for (int k = 0; k < 16; k++){
    float h0k = pb[k] + x0 * pw[0*16+k] + x1 * pw[1*16+k] + x2 * pw[2*16+k];
    a += h0k * g1w[k*16 + c];
  }
  hp1[idx] = a;
}

// es/ed from hp: one THREAD per (row, head)
template<int F, int D>
__global__ __launch_bounds__(256) void k_esed(const float* __restrict__ hp,
    const float* __restrict__ asrc, const float* __restrict__ adst,
    float* __restrict__ es, float* __restrict__ ed){
  int idx = blockIdx.x * 256 + threadIdx.x;           // NROWS*4
  if (idx >= NROWS * 4) return;
  int row = idx >> 2, h = idx & 3;
  float s = 0.f, dsum = 0.f;
  for (int d = 0; d < D; d++){
    float v = hp[row*F + h*D + d];
    s    += v * asrc[h*D + d];
    dsum += v * adst[h*D + d];
  }
  es[idx] = s;
  ed[idx] = dsum;
}

// K4: hp2[row,c] = x1[row,:] dot g2_w[:,c]
__global__ __launch_bounds__(256) void k_pre2a(const float* __restrict__ x1,
    const float* __restrict__ g2w, float* __restrict__ hp2){
  int idx = blockIdx.x * 256 + threadIdx.x;           // 819200
  if (idx >= NROWS * 32) return;
  int row = idx >> 5, c = idx & 31;
  float a = 0.f;
  for (int k = 0; k < 16; k++) a += x1[row*16 + k] * g2w[k*32 + c];
  hp2[idx] = a;
}

// K3/K5: GAT masked-softmax attention, one THREAD per (row, head).
template<int D, bool GELU>
__global__ __launch_bounds__(200) void k_gat(const float* __restrict__ hp,
    const float* __restrict__ es, const float* __restrict__ ed,
    const unsigned char* __restrict__ mask, const float* __restrict__ bias,
    float* __restrict__ outp){
  constexpr int F = 4 * D;
  __shared__ float sh[NN * F];
  __shared__ float se[NN * 4];
  __shared__ float sb[F];
  const int tid = threadIdx.x;
  const int b = blockIdx.x >> 3, chunk = blockIdx.x & 7;
  const float* hb = hp + (size_t)b * NN * F;
  for (int idx = tid; idx < NN * F; idx += 200) sh[idx] = hb[idx];
  const float* eb = es + (size_t)b * NN * 4;
  for (int idx = tid; idx < NN * 4; idx += 200) se[idx] = eb[idx];
  if (tid < F) sb[tid] = bias[tid];
  __syncthreads();
  const int li = tid >> 2, h = tid & 3;
  const int i = chunk * 50 + li;
  const int row = b * NN + i;
  const float edh = ed[(size_t)row * 4 + h];
  const unsigned char* mr = mask + (size_t)i * NN;
  float mx = -1e30f;
  for (int j = 0; j < NN; j++)
    if (mr[j]) mx = fmaxf(mx, lrelu02(edh + se[j*4+h]));
  float den = 0.f;
  float acc[D];
  #pragma unroll
  for (int d = 0; d < D; d++) acc[d] = 0.f;
  for (int j = 0; j < NN; j++){
    if (mr[j]){
      float pv = expf(lrelu02(edh + se[j*4+h]) - mx);
      den += pv;
      #pragma unroll
      for (int d = 0; d < D; d++) acc[d] += pv * sh[j*F + h*D + d];
    }
  }
  float invd = 1.0f / den;
  #pragma unroll
  for (int d = 0; d < D; d++){
    float v = acc[d] * invd + sb[h*D + d];
    if (GELU) v = gelu_exact(v);
    outp[(size_t)row * F + h*D + d] = v;
  }
}

struct TW { const float* p[20]; };
// order: 0 wq,1 bq,2 wk,3 bk,4 wv,5 bv,6 wo,7 bo,8 ln1g,9 ln1b,
//        10 fw1,11 fb1,12 fw2,13 fb2,14 ln2g,15 ln2b,16 rw1,17 rb1,18 rw2,19 rb2

// K6: fused temporal transformer; f32 output (reference returns float32!)
__global__ __launch_bounds__(512) void k_trans2(const float* __restrict__ h2, TW tw,
                                                float* __restrict__ out){
  __shared__ float Wq[1024], Wk[1024], Wv[1024], Wo[1024];
  __shared__ float Fw1[2048], Fw2[2048], Rw1[512];
  __shared__ float Bq[32], Bk[32], Bv[32], Bo[32], L1g[32], L1b[32];
  __shared__ float Fb1[64], Fb2[32], L2g[32], L2b[32], Rb1v[16], Rw2[16];
  __shared__ float Rb2s;
  __shared__ float T[512], QQ[512], KK[512], VV[512], SC[512], AT[512], X[512], Y[512];
  __shared__ float F2[1024];
  __shared__ float MX[32], DEN[32], M[32], RH[16];
  const int tid = threadIdx.x;
  const int p = blockIdx.x;
  for (int i = tid; i < 1024; i += 512){
    Wq[i] = tw.p[0][i]; Wk[i] = tw.p[2][i]; Wv[i] = tw.p[4][i]; Wo[i] = tw.p[6][i];
  }
  for (int i = tid; i < 2048; i += 512){ Fw1[i] = tw.p[10][i]; Fw2[i] = tw.p[12][i]; }
  if (tid < 512) Rw1[tid] = tw.p[16][tid];
  if (tid < 32){
    Bq[tid] = tw.p[1][tid]; Bk[tid] = tw.p[3][tid]; Bv[tid] = tw.p[5][tid]; Bo[tid] = tw.p[7][tid];
    L1g[tid] = tw.p[8][tid]; L1b[tid] = tw.p[9][tid]; Fb2[tid] = tw.p[13][tid];
    L2g[tid] = tw.p[14][tid]; L2b[tid] = tw.p[15][tid];
  }
  if (tid < 64) Fb1[tid] = tw.p[11][tid];
  if (tid < 16){ Rb1v[tid] = tw.p[17][tid]; Rw2[tid] = tw.p[18][tid]; }
  if (tid == 0) Rb2s = tw.p[19][0];
  const int s = tid >> 5, o = tid & 31;
  T[tid] = h2[(size_t)(p * 16 + s) * 32 + o];
  __syncthreads();
  // QKV projections (o = h*16+d)
  {
    float aq = Bq[o], ak = Bk[o], av = Bv[o];
    for (int f = 0; f < 32; f++){
      float tv = T[s*32 + f];
      aq += tv * Wq[f*32 + o];
      ak += tv * Wk[f*32 + o];
      av += tv * Wv[f*32 + o];
    }
    QQ[tid] = aq; KK[tid] = ak; VV[tid] = av;
  }
  __syncthreads();
  // scores: tid = (h*16+i)*16 + j
  {
    int h = tid >> 8, i = (tid >> 4) & 15, j = tid & 15;
    float d = 0.f;
    for (int dk = 0; dk < 16; dk++) d += QQ[i*32 + h*16 + dk] * KK[j*32 + h*16 + dk];
    SC[tid] = d * 0.25f;
  }
  __syncthreads();
  if (tid < 32){
    float mx = -1e30f;
    for (int j = 0; j < 16; j++) mx = fmaxf(mx, SC[tid*16 + j]);
    float den = 0.f;
    for (int j = 0; j < 16; j++) den += expf(SC[tid*16 + j] - mx);
    MX[tid] = mx; DEN[tid] = den;
  }
  __syncthreads();
  {
    int hi = tid >> 4;
    SC[tid] = expf(SC[tid] - MX[hi]) / DEN[hi];
  }
  __syncthreads();
  {
    int h = o >> 4;
    float a = 0.f;
    for (int j = 0; j < 16; j++) a += SC[(h*16 + s)*16 + j] * VV[j*32 + o];
    AT[tid] = a;
  }
  __syncthreads();
  {
    float v = Bo[o];
    for (int i2 = 0; i2 < 32; i2++) v += AT[s*32 + i2] * Wo[i2*32 + o];
    X[tid] = T[tid] + v;
  }
  __syncthreads();
  {
    float sm = 0.f, sq = 0.f;
    for (int f = 0; f < 32; f++){ float xv = X[s*32 + f]; sm += xv; sq += xv*xv; }
    float mean = sm * (1.f/32.f), var = sq * (1.f/32.f) - mean*mean;
    float inv = 1.0f / sqrtf(var + 1e-3f);
    T[tid] = (X[tid] - mean) * inv * L1g[o] + L1b[o];
  }
  __syncthreads();
  for (int c2 = tid; c2 < 1024; c2 += 512){
    int s3 = c2 >> 6, c = c2 & 63;
    float a = Fb1[c];
    for (int f = 0; f < 32; f++) a += T[s3*32 + f] * Fw1[f*64 + c];
    F2[c2] = gelu_exact(a);
  }
  __syncthreads();
  {
    float v = Fb2[o];
    for (int c = 0; c < 64; c++) v += F2[s*64 + c] * Fw2[c*32 + o];
    X[tid] = T[tid] + v;
  }
  __syncthreads();
  {
    float sm = 0.f, sq = 0.f;
    for (int f = 0; f < 32; f++){ float xv = X[s*32 + f]; sm += xv; sq += xv*xv; }
    float mean = sm * (1.f/32.f), var = sq * (1.f/32.f) - mean*mean;
    float inv = 1.0f / sqrtf(var + 1e-3f);
    Y[tid] = (X[tid] - mean) * inv * L2g[o] + L2b[o];
  }
  __syncthreads();
  if (tid < 32){
    float a = 0.f;
    for (int s2 = 0; s2 < 16; s2++) a += Y[s2*32 + tid];
    M[tid] = a * (1.f/16.f);
  }
  __syncthreads();
  if (tid < 16){
    float hid = Rb1v[tid];
    for (int o2 = 0; o2 < 32; o2++) hid += M[o2] * Rw1[o2*16 + tid];
    RH[tid] = gelu_exact(hid) * Rw2[tid];
  }
  __syncthreads();
  if (tid == 0){
    float a = Rb2s;
    for (int k = 0; k < 16; k++) a += RH[k];
    out[p] = a;          // f32 output — reference returns float32
  }
}

extern "C" void kernel_launch(void* const* d_in, const int* in_sizes, int n_in,
                              void* d_out, int out_size, void* d_ws, size_t ws_size,
                              hipStream_t stream){
  const float* x    = (const float*)d_in[0];
  const float* adj  = (const float*)d_in[1];
  const float* pw   = (const float*)d_in[2];
  const float* pb   = (const float*)d_in[3];
  const float* g1w  = (const float*)d_in[4];
  const float* g1as = (const float*)d_in[5];
  const float* g1ad = (const float*)d_in[6];
  const float* g1b  = (const float*)d_in[7];
  const float* g2w  = (const float*)d_in[8];
  const float* g2as = (const float*)d_in[9];
  const float* g2ad = (const float*)d_in[10];
  const float* g2b  = (const float*)d_in[11];

  char* ws = (char*)d_ws;
  unsigned char* mask = (unsigned char*)(ws + OFF_MASK);
  float* hp1 = (float*)(ws + OFF_HP1);
  float* es1 = (float*)(ws + OFF_ES1);
  float* ed1 = (float*)(ws + OFF_ED1);
  float* x1  = (float*)(ws + OFF_X1);
  float* hp2 = (float*)(ws + OFF_HP2);
  float* es2 = (float*)(ws + OFF_ES2);
  float* ed2 = (float*)(ws + OFF_ED2);
  float* h2  = (float*)(ws + OFF_H2);

  TW tw;
  for (int t = 0; t < 20; t++) tw.p[t] = (const float*)d_in[12 + t];

  hipLaunchKernelGGL(k_mask2, dim3(NN), dim3(512), 0, stream, adj, mask);
  hipLaunchKernelGGL(k_pre1a, dim3(1600), dim3(256), 0, stream, x, pw, pb, g1w, hp1);
  hipLaunchKernelGGL((k_esed<16,4>), dim3(400), dim3(256), 0, stream, hp1, g1as, g1ad, es1, ed1);
  hipLaunchKernelGGL((k_gat<4, true>),  dim3(512), dim3(200), 0, stream, hp1, es1, ed1, mask, g1b, x1);
  hipLaunchKernelGGL(k_pre2a, dim3(3200), dim3(256), 0, stream, x1, g2w, hp2);
  hipLaunchKernelGGL((k_esed<32,8>), dim3(400), dim3(256), 0, stream, hp2, g2as, g2ad, es2, ed2);
  hipLaunchKernelGGL((k_gat<8, false>), dim3(512), dim3(200), 0, stream, hp2, es2, ed2, mask, g2b, h2);
  hipLaunchKernelGGL(k_trans2, dim3(NSEQ), dim3(512), 0, stream, h2, tw, (float*)d_out);
}